// Round 21
// baseline (115.558 us; speedup 1.0000x reference)
//
#include <hip/hip_runtime.h>

// B=2, T=2048, C=1024, H=16, HD=64. Inputs f32, output f32.
// convert2 (x,Wqkv), QKV GEMM (BK=64, XOR-swizzled LDS, XCD-local regions,
// fused RoPE/split epilogue, V^T slot-ordered, tail blocks convert W_proj),
// flash attention (QBLK=128: 2x16-row chunks/wave share staged K/V tiles ->
// halved staging traffic, 2x MFMA per staged byte), proj GEMM -> f32.
// ws plan (48 MiB): [0,8M) xb | [8,14M) wqkvb | [14,16M) wprojb | [16,24M) qro
//                   | [24,32M) kro | [32,40M) vt | [40,48M) oat

typedef short  bf16x8 __attribute__((ext_vector_type(8)));
typedef float  f32x4  __attribute__((ext_vector_type(4)));
typedef unsigned short u16x4 __attribute__((ext_vector_type(4)));

#define B_  2
#define T_  2048
#define H_  16
#define HD_ 64
#define NINF (-__builtin_inff())

static __device__ __forceinline__ unsigned short f2bf(float f) {
    union { float f; unsigned u; } v; v.f = f;
    unsigned r = v.u + 0x7fffu + ((v.u >> 16) & 1u);   // RNE
    return (unsigned short)(r >> 16);
}

#define GLOAD_LDS16(gp, lp)                                                              \
    __builtin_amdgcn_global_load_lds((const __attribute__((address_space(1))) void*)(gp), \
                                     (__attribute__((address_space(3))) void*)(lp), 16, 0, 0)

// ---------------- f32 -> bf16 convert of x, W_qkv (single launch) ----------------
__global__ void convert2(const float* __restrict__ x, const float* __restrict__ wqkv,
                         unsigned short* __restrict__ xb, unsigned short* __restrict__ wqkvb) {
    int i = blockIdx.x * blockDim.x + threadIdx.x;     // float4 index, total 1835008
    const float* src; unsigned short* dst; int off;
    if (i < 1048576) { src = x;    dst = xb;    off = i; }
    else             { src = wqkv; dst = wqkvb; off = i - 1048576; }
    float4 f = ((const float4*)src)[off];
    u16x4 o; o[0] = f2bf(f.x); o[1] = f2bf(f.y); o[2] = f2bf(f.z); o[3] = f2bf(f.w);
    ((u16x4*)dst)[off] = o;
}

// ---------------- QKV GEMM (r17 verified) + W_proj-convert tail blocks ------
__global__ __launch_bounds__(256) void gemm_qkv(const unsigned short* __restrict__ A,
                                                const unsigned short* __restrict__ Bm,
                                                const float* __restrict__ fa,
                                                const float* __restrict__ fb,
                                                unsigned short* __restrict__ Qo,
                                                unsigned short* __restrict__ Ko,
                                                unsigned short* __restrict__ Vt,
                                                const float* __restrict__ wproj,
                                                unsigned short* __restrict__ wprojb) {
    __shared__ __align__(16) unsigned short As[128 * 64];   // 16 KB
    __shared__ __align__(16) unsigned short Bs[128 * 64];
    const int bid = blockIdx.x;
    if (bid >= 768) {                        // tail: convert W_proj (1048576 f32)
        int base = (bid - 768) * 256 + threadIdx.x;   // 16384 threads x 16 float4
#pragma unroll
        for (int k = 0; k < 16; k++) {
            int u = base + k * 16384;
            float4 f = ((const float4*)wproj)[u];
            u16x4 o; o[0] = f2bf(f.x); o[1] = f2bf(f.y); o[2] = f2bf(f.z); o[3] = f2bf(f.w);
            ((u16x4*)wprojb)[u] = o;
        }
        return;
    }

    const int K = 1024;
    const int tid  = threadIdx.x;
    const int w    = tid >> 6;
    const int lane = tid & 63;
    const int r    = lane & 15, g = lane >> 4;

    // XCD-local region mapping (bijective): 768 = 8 XCD x (8m x 12n)
    const int xcd  = bid & 7;
    const int i_   = bid >> 3;                 // 0..95
    const int m0   = ((xcd >> 1) * 8 + i_ / 12) * 128;
    const int n0   = ((xcd & 1) * 12 + i_ % 12) * 128;
    const int wm   = (w >> 1) * 64, wn = (w & 1) * 64;

    f32x4 acc[4][4];
#pragma unroll
    for (int i = 0; i < 4; i++)
#pragma unroll
        for (int j = 0; j < 4; j++) acc[i][j] = (f32x4){0.f, 0.f, 0.f, 0.f};

    const int rowS = tid >> 3;
    const int csS  = (tid & 7) ^ (rowS & 7);
    const int t8e  = tid * 8;
    const unsigned short* ga = A  + (size_t)(m0 + rowS) * K + csS * 8;
    const unsigned short* gb = Bm + (size_t)(n0 + rowS) * K + csS * 8;

    int roff[4][2];
#pragma unroll
    for (int mi = 0; mi < 4; mi++)
#pragma unroll
        for (int kk = 0; kk < 2; kk++)
            roff[mi][kk] = (mi * 16 + r) * 64 + (((4 * kk + g) ^ (r & 7)) * 8);

    for (int k0 = 0; k0 < K; k0 += 64) {
        __syncthreads();
        GLOAD_LDS16(ga + k0,            &As[t8e]);
        GLOAD_LDS16(ga + 32 * K + k0,   &As[2048 + t8e]);
        GLOAD_LDS16(ga + 64 * K + k0,   &As[4096 + t8e]);
        GLOAD_LDS16(ga + 96 * K + k0,   &As[6144 + t8e]);
        GLOAD_LDS16(gb + k0,            &Bs[t8e]);
        GLOAD_LDS16(gb + 32 * K + k0,   &Bs[2048 + t8e]);
        GLOAD_LDS16(gb + 64 * K + k0,   &Bs[4096 + t8e]);
        GLOAD_LDS16(gb + 96 * K + k0,   &Bs[6144 + t8e]);
        __syncthreads();

#pragma unroll
        for (int kk = 0; kk < 2; kk++) {
            bf16x8 a[4], b[4];
#pragma unroll
            for (int mi = 0; mi < 4; mi++) a[mi] = *(const bf16x8*)&As[wm * 64 + roff[mi][kk]];
#pragma unroll
            for (int ni = 0; ni < 4; ni++) b[ni] = *(const bf16x8*)&Bs[wn * 64 + roff[ni][kk]];
#pragma unroll
            for (int mi = 0; mi < 4; mi++)
#pragma unroll
                for (int ni = 0; ni < 4; ni++)
                    acc[mi][ni] = __builtin_amdgcn_mfma_f32_16x16x32_bf16(a[mi], b[ni], acc[mi][ni], 0, 0, 0);
        }
    }

    // -------- fused epilogue --------
    const float* fcos = (fa[0] > 0.5f) ? fa : fb;   // cos row at t=0 is all 1.0
    const float* fsin = (fa[0] > 0.5f) ? fb : fa;
    const int region = n0 >> 10;                    // 0=Q, 1=K, 2=V (block-uniform)

    if (region < 2) {
        unsigned short* dst = region ? Ko : Qo;
        const float sgn = (r & 1) ? 1.f : -1.f;     // out = v*c + sgn*vp*s
#pragma unroll
        for (int mi = 0; mi < 4; mi++) {
            int row0 = m0 + wm + mi * 16 + 4 * g;
            int b    = row0 >> 11;
            int t0   = row0 & 2047;
#pragma unroll
            for (int ni = 0; ni < 4; ni++) {
                int nn = (n0 & 1023) + wn + ni * 16 + r;
                int h  = nn >> 6, dd = nn & 63;
                int i  = dd >> 1;
                size_t obase = ((size_t)((b * 16 + h) * 2048 + t0)) * 64 + dd;
#pragma unroll
                for (int j = 0; j < 4; j++) {
                    float c = fcos[(t0 + j) * 32 + i];
                    float s = fsin[(t0 + j) * 32 + i];
                    float v  = acc[mi][ni][j];
                    float vp = __shfl_xor(v, 1);
                    float out = __builtin_fmaf(sgn * vp, s, v * c);
                    dst[obase + (size_t)j * 64] = f2bf(out);
                }
            }
        }
    } else {
#pragma unroll
        for (int mi = 0; mi < 4; mi++) {
            int row0 = m0 + wm + mi * 16 + 4 * g;
            int b    = row0 >> 11;
            int t0   = row0 & 2047;
            int tp   = (t0 & ~31) + 8 * ((t0 & 15) >> 2) + 4 * ((t0 & 31) >> 4);
#pragma unroll
            for (int ni = 0; ni < 4; ni++) {
                int nn = (n0 & 1023) + wn + ni * 16 + r;
                int h  = nn >> 6, dd = nn & 63;
                u16x4 ov;
#pragma unroll
                for (int j = 0; j < 4; j++) ov[j] = f2bf(acc[mi][ni][j]);
                *(u16x4*)(Vt + ((size_t)((b * 16 + h) * 64 + dd)) * 2048 + tp) = ov;
            }
        }
    }
}

// ---------------- proj GEMM (BK=64, XCD-local): C = A*B^T + bias -> f32 ----------------
__global__ __launch_bounds__(256) void gemm_nt(const unsigned short* __restrict__ A,
                                               const unsigned short* __restrict__ Bm,
                                               float* __restrict__ Cm,
                                               const float* __restrict__ bias,
                                               int M, int N, int K) {
    __shared__ __align__(16) unsigned short As[128 * 64];
    __shared__ __align__(16) unsigned short Bs[128 * 64];
    const int tid  = threadIdx.x;
    const int w    = tid >> 6;
    const int lane = tid & 63;
    const int r    = lane & 15, g = lane >> 4;

    const int bid  = blockIdx.x;
    const int xcd  = bid & 7;
    const int i_   = bid >> 3;                 // 0..31
    const int m0   = ((xcd >> 1) * 8 + (i_ >> 2)) * 128;
    const int n0   = ((xcd & 1) * 4 + (i_ & 3)) * 128;
    const int wm   = (w >> 1) * 64, wn = (w & 1) * 64;

    f32x4 acc[4][4];
#pragma unroll
    for (int i = 0; i < 4; i++)
#pragma unroll
        for (int j = 0; j < 4; j++) acc[i][j] = (f32x4){0.f, 0.f, 0.f, 0.f};

    const int rowS = tid >> 3;
    const int csS  = (tid & 7) ^ (rowS & 7);
    const int t8e  = tid * 8;
    const unsigned short* ga = A  + (size_t)(m0 + rowS) * K + csS * 8;
    const unsigned short* gb = Bm + (size_t)(n0 + rowS) * K + csS * 8;

    int roff[4][2];
#pragma unroll
    for (int mi = 0; mi < 4; mi++)
#pragma unroll
        for (int kk = 0; kk < 2; kk++)
            roff[mi][kk] = (mi * 16 + r) * 64 + (((4 * kk + g) ^ (r & 7)) * 8);

    for (int k0 = 0; k0 < K; k0 += 64) {
        __syncthreads();
        GLOAD_LDS16(ga + k0,            &As[t8e]);
        GLOAD_LDS16(ga + 32 * K + k0,   &As[2048 + t8e]);
        GLOAD_LDS16(ga + 64 * K + k0,   &As[4096 + t8e]);
        GLOAD_LDS16(ga + 96 * K + k0,   &As[6144 + t8e]);
        GLOAD_LDS16(gb + k0,            &Bs[t8e]);
        GLOAD_LDS16(gb + 32 * K + k0,   &Bs[2048 + t8e]);
        GLOAD_LDS16(gb + 64 * K + k0,   &Bs[4096 + t8e]);
        GLOAD_LDS16(gb + 96 * K + k0,   &Bs[6144 + t8e]);
        __syncthreads();

#pragma unroll
        for (int kk = 0; kk < 2; kk++) {
            bf16x8 a[4], b[4];
#pragma unroll
            for (int mi = 0; mi < 4; mi++) a[mi] = *(const bf16x8*)&As[wm * 64 + roff[mi][kk]];
#pragma unroll
            for (int ni = 0; ni < 4; ni++) b[ni] = *(const bf16x8*)&Bs[wn * 64 + roff[ni][kk]];
#pragma unroll
            for (int mi = 0; mi < 4; mi++)
#pragma unroll
                for (int ni = 0; ni < 4; ni++)
                    acc[mi][ni] = __builtin_amdgcn_mfma_f32_16x16x32_bf16(a[mi], b[ni], acc[mi][ni], 0, 0, 0);
        }
    }

#pragma unroll
    for (int mi = 0; mi < 4; mi++) {
        int row = m0 + wm + mi * 16 + 4 * g;
#pragma unroll
        for (int ni = 0; ni < 4; ni++) {
            int col = n0 + wn + ni * 16 + r;
            float bv = bias[col];
#pragma unroll
            for (int j = 0; j < 4; j++)
                Cm[(size_t)(row + j) * N + col] = acc[mi][ni][j] + bv;
        }
    }
}

// ---------------- flash attention, QBLK=128 x KVBLK=128, dual 16-row chunks ----------
// 512 blocks = 8 XCD x 32 y x 2 q. Block p (0..15) covers q-rows [128p,128p+128);
// wave w owns chunks A=[128p+32w, +16) and B=[+16,+32). K/V tiles staged once,
// shared by both chunks (2x MFMA per staged byte; total tiles/head 272 -> 136).
// CU's two blocks have p and 15-p -> 17 trips/CU uniform. Diagonal tile kt==p.
template <bool DIAG>
static __device__ __forceinline__ void softmax128(const f32x4 s[8], int key0, int qrow,
                                                  float& m, float& l,
                                                  f32x4 o[4], bf16x8 pf[4], int g) {
    const float SCL = 0.125f * 1.4426950408889634f;   // HD^-0.5 * log2(e)
    float sv[32];
#pragma unroll
    for (int ks = 0; ks < 8; ks++)
#pragma unroll
        for (int j = 0; j < 4; j++) {
            float x = s[ks][j];
            if (DIAG && (key0 + ks * 16 + 4 * g + j > qrow)) x = NINF;
            sv[ks * 4 + j] = x;
        }
    float t16[16];
#pragma unroll
    for (int i = 0; i < 16; i++) t16[i] = fmaxf(sv[i], sv[i + 16]);
#pragma unroll
    for (int i = 0; i < 8; i++) t16[i] = fmaxf(t16[i], t16[i + 8]);
#pragma unroll
    for (int i = 0; i < 4; i++) t16[i] = fmaxf(t16[i], t16[i + 4]);
    float tm = fmaxf(fmaxf(t16[0], t16[1]), fmaxf(t16[2], t16[3]));
    tm = fmaxf(tm, __shfl_xor(tm, 16));
    tm = fmaxf(tm, __shfl_xor(tm, 32));

    float msc;
    if (__all(tm <= m)) {                 // exact skip: alpha == 1 for every row
        msc = m * SCL;
    } else {
        float mnew  = fmaxf(m, tm);
        float alpha = __builtin_amdgcn_exp2f((m - mnew) * SCL);
        l *= alpha;
#pragma unroll
        for (int ch = 0; ch < 4; ch++) o[ch] *= alpha;
        m = mnew;
        msc = mnew * SCL;
    }
    float p[32];
#pragma unroll
    for (int i = 0; i < 32; i++) p[i] = __builtin_amdgcn_exp2f(__builtin_fmaf(sv[i], SCL, -msc));
    float ps = 0.f;
#pragma unroll
    for (int i = 0; i < 32; i += 4) ps += ((p[i] + p[i + 1]) + (p[i + 2] + p[i + 3]));
    l += ps;
#pragma unroll
    for (int kb = 0; kb < 4; kb++) {
        union { unsigned w[4]; bf16x8 v; } u;
        asm("v_cvt_pk_bf16_f32 %0, %1, %2" : "=v"(u.w[0]) : "v"(p[8 * kb + 0]), "v"(p[8 * kb + 1]));
        asm("v_cvt_pk_bf16_f32 %0, %1, %2" : "=v"(u.w[1]) : "v"(p[8 * kb + 2]), "v"(p[8 * kb + 3]));
        asm("v_cvt_pk_bf16_f32 %0, %1, %2" : "=v"(u.w[2]) : "v"(p[8 * kb + 4]), "v"(p[8 * kb + 5]));
        asm("v_cvt_pk_bf16_f32 %0, %1, %2" : "=v"(u.w[3]) : "v"(p[8 * kb + 6]), "v"(p[8 * kb + 7]));
        pf[kb] = u.v;
    }
}

__global__ __launch_bounds__(256, 2) void attn_fwd(const unsigned short* __restrict__ Q,
                                                   const unsigned short* __restrict__ Kk,
                                                   const unsigned short* __restrict__ Vt,
                                                   unsigned short* __restrict__ O) {
    __shared__ __align__(16) unsigned short Ks[2][8192];   // dbuf: 128 keys x 64 d (swizzled)
    __shared__ __align__(16) unsigned short Vs[2][8192];   // dbuf: 64 d x 128 keys (swizzled, slot-ordered)

    const int w    = threadIdx.x >> 6;
    const int lane = threadIdx.x & 63;
    const int l15  = lane & 15, g = lane >> 4;

    const int bid = blockIdx.x;                // 0..511
    const int x   = bid & 7;
    const int y   = (bid >> 3) & 31;
    const int q   = bid >> 8;                  // 0..1
    const int bh  = x | ((y & 3) << 3);        // 32 bh, 4 per XCD
    const int z   = y >> 2;                    // 0..7
    const int p   = q ? 15 - z : z;            // CU pair sums to 17 trips
    const int b   = bh >> 4, h = bh & 15;

    const unsigned short* Qb = Q  + (size_t)bh * T_ * HD_;
    const unsigned short* Kb = Kk + (size_t)bh * T_ * HD_;
    const unsigned short* Vb = Vt + (size_t)bh * HD_ * T_;

    const int qrowA = p * 128 + 32 * w + l15;
    const int qrowB = qrowA + 16;
    bf16x8 qA0 = *(const bf16x8*)(Qb + (size_t)qrowA * 64 + 8 * g);
    bf16x8 qA1 = *(const bf16x8*)(Qb + (size_t)qrowA * 64 + 32 + 8 * g);
    bf16x8 qB0 = *(const bf16x8*)(Qb + (size_t)qrowB * 64 + 8 * g);
    bf16x8 qB1 = *(const bf16x8*)(Qb + (size_t)qrowB * 64 + 32 + 8 * g);

    f32x4 oA[4], oB[4];
#pragma unroll
    for (int ch = 0; ch < 4; ch++) { oA[ch] = (f32x4){0,0,0,0}; oB[ch] = (f32x4){0,0,0,0}; }
    float mA = NINF, lA = 0.f, mB = NINF, lB = 0.f;

    int koff[8][2];                            // K: row=16ks+l15, 128B rows, chunks {g, 4+g}
#pragma unroll
    for (int i = 0; i < 8; i++) {
        int row = 16 * i + l15;
        koff[i][0] = row * 128 + ((g ^ (row & 7)) << 4);
        koff[i][1] = row * 128 + (((4 + g) ^ (row & 7)) << 4);
    }
    int voff[4][4];                            // V: row=16ch+l15, 256B rows, chunk kb*4+g
#pragma unroll
    for (int ch = 0; ch < 4; ch++) {
        int row = 16 * ch + l15;
#pragma unroll
        for (int kb = 0; kb < 4; kb++)
            voff[ch][kb] = row * 256 + (((kb * 4 + g) ^ (row & 7)) << 4);
    }

    const int t   = threadIdx.x;
    const int rK0 = t >> 3;
    const int csK = (t & 7) ^ (rK0 & 7);
    const int rV0 = t >> 4;
    const int csV = (t & 15) ^ (rV0 & 7);
    const int t8e = t * 8;
    const unsigned short* sK = Kb + (size_t)rK0 * 64 + csK * 8;     // + key0*64 + 2048*k
    const unsigned short* sV = Vb + (size_t)rV0 * 2048 + csV * 8;   // + key0 + 32768*k

#define STAGE_TILE(bb, key0_)                                                     \
    do {                                                                          \
        GLOAD_LDS16(sK + (size_t)(key0_) * 64,         &Ks[bb][t8e]);             \
        GLOAD_LDS16(sK + (size_t)(key0_) * 64 + 2048,  &Ks[bb][2048 + t8e]);      \
        GLOAD_LDS16(sK + (size_t)(key0_) * 64 + 4096,  &Ks[bb][4096 + t8e]);      \
        GLOAD_LDS16(sK + (size_t)(key0_) * 64 + 6144,  &Ks[bb][6144 + t8e]);      \
        GLOAD_LDS16(sV + (key0_),                      &Vs[bb][t8e]);             \
        GLOAD_LDS16(sV + (key0_) + 32768,              &Vs[bb][2048 + t8e]);      \
        GLOAD_LDS16(sV + (key0_) + 65536,              &Vs[bb][4096 + t8e]);      \
        GLOAD_LDS16(sV + (key0_) + 98304,              &Vs[bb][6144 + t8e]);      \
    } while (0)

    STAGE_TILE(0, 0);
    __syncthreads();                   // drains vmcnt -> tile 0 ready

    for (int kt = 0; kt <= p; ++kt) {
        const int key0 = kt * 128;
        const int cur  = kt & 1;
        if (kt < p) STAGE_TILE(cur ^ 1, key0 + 128);   // prefetch next tile

        const char* KsB = (const char*)&Ks[cur][0];
        const char* VsB = (const char*)&Vs[cur][0];

        f32x4 z4 = (f32x4){0, 0, 0, 0};
        f32x4 sA[8], sB[8];
#pragma unroll
        for (int ks = 0; ks < 8; ks++) {               // K frags shared by both chunks
            bf16x8 kf0 = *(const bf16x8*)(KsB + koff[ks][0]);
            bf16x8 kf1 = *(const bf16x8*)(KsB + koff[ks][1]);
            sA[ks] = __builtin_amdgcn_mfma_f32_16x16x32_bf16(kf0, qA0, z4, 0, 0, 0);
            sA[ks] = __builtin_amdgcn_mfma_f32_16x16x32_bf16(kf1, qA1, sA[ks], 0, 0, 0);
            sB[ks] = __builtin_amdgcn_mfma_f32_16x16x32_bf16(kf0, qB0, z4, 0, 0, 0);
            sB[ks] = __builtin_amdgcn_mfma_f32_16x16x32_bf16(kf1, qB1, sB[ks], 0, 0, 0);
        }

        bf16x8 pfA[4], pfB[4];
        if (kt == p) {
            softmax128<true >(sA, key0, qrowA, mA, lA, oA, pfA, g);
            softmax128<true >(sB, key0, qrowB, mB, lB, oB, pfB, g);
        } else {
            softmax128<false>(sA, key0, qrowA, mA, lA, oA, pfA, g);
            softmax128<false>(sB, key0, qrowB, mB, lB, oB, pfB, g);
        }

#pragma unroll
        for (int ch = 0; ch < 4; ch++) {               // V frags shared by both chunks
            bf16x8 v0 = *(const bf16x8*)(VsB + voff[ch][0]);
            bf16x8 v1 = *(const bf16x8*)(VsB + voff[ch][1]);
            bf16x8 v2 = *(const bf16x8*)(VsB + voff[ch][2]);
            bf16x8 v3 = *(const bf16x8*)(VsB + voff[ch][3]);
            oA[ch] = __builtin_amdgcn_mfma_f32_16x16x32_bf16(v0, pfA[0], oA[ch], 0, 0, 0);
            oA[ch] = __builtin_amdgcn_mfma_f32_16x16x32_bf16(v1, pfA[1], oA[ch], 0, 0, 0);
            oA[ch] = __builtin_amdgcn_mfma_f32_16x16x32_bf16(v2, pfA[2], oA[ch], 0, 0, 0);
            oA[ch] = __builtin_amdgcn_mfma_f32_16x16x32_bf16(v3, pfA[3], oA[ch], 0, 0, 0);
            oB[ch] = __builtin_amdgcn_mfma_f32_16x16x32_bf16(v0, pfB[0], oB[ch], 0, 0, 0);
            oB[ch] = __builtin_amdgcn_mfma_f32_16x16x32_bf16(v1, pfB[1], oB[ch], 0, 0, 0);
            oB[ch] = __builtin_amdgcn_mfma_f32_16x16x32_bf16(v2, pfB[2], oB[ch], 0, 0, 0);
            oB[ch] = __builtin_amdgcn_mfma_f32_16x16x32_bf16(v3, pfB[3], oB[ch], 0, 0, 0);
        }

        __syncthreads();    // drains vmcnt (next tile staged) + read/write fence
    }
#undef STAGE_TILE

    lA += __shfl_xor(lA, 16); lA += __shfl_xor(lA, 32);
    lB += __shfl_xor(lB, 16); lB += __shfl_xor(lB, 32);
    float invA = 1.f / lA, invB = 1.f / lB;

    size_t obA = (((size_t)b * T_ + qrowA) * H_ + h) * HD_;
    size_t obB = (((size_t)b * T_ + qrowB) * H_ + h) * HD_;
#pragma unroll
    for (int ch = 0; ch < 4; ch++) {
        int d0 = 16 * ch + 4 * g;
        u16x4 va_, vb_;
#pragma unroll
        for (int jj = 0; jj < 4; jj++) {
            va_[jj] = f2bf(oA[ch][jj] * invA);
            vb_[jj] = f2bf(oB[ch][jj] * invB);
        }
        *(u16x4*)(O + obA + d0) = va_;
        *(u16x4*)(O + obB + d0) = vb_;
    }
}

extern "C" void kernel_launch(void* const* d_in, const int* in_sizes, int n_in,
                              void* d_out, int out_size, void* d_ws, size_t ws_size,
                              hipStream_t stream) {
    (void)out_size;
    const float *x = nullptr, *wqkv = nullptr, *wproj = nullptr, *bproj = nullptr;
    const float *fa = nullptr, *fb = nullptr;
    for (int i = 0; i < n_in; i++) {
        switch (in_sizes[i]) {
            case 4194304: x     = (const float*)d_in[i]; break;
            case 3145728: wqkv  = (const float*)d_in[i]; break;
            case 1048576: wproj = (const float*)d_in[i]; break;
            case 1024:    bproj = (const float*)d_in[i]; break;
            case 65536:   if (!fa) fa = (const float*)d_in[i]; else fb = (const float*)d_in[i]; break;
            default: break;
        }
    }
    if (!x || !wqkv || !wproj || !bproj || !fa || !fb) return;
    if (ws_size < (size_t)48 * 1024 * 1024) return;

    char* ws = (char*)d_ws;
    const size_t MB = 1024 * 1024;
    unsigned short* xb     = (unsigned short*)(ws);            // [0,8M)
    unsigned short* wqkvb  = (unsigned short*)(ws + 8  * MB);  // [8,14M)
    unsigned short* wprojb = (unsigned short*)(ws + 14 * MB);  // [14,16M)
    unsigned short* qro    = (unsigned short*)(ws + 16 * MB);  // [16,24M)
    unsigned short* kro    = (unsigned short*)(ws + 24 * MB);  // [24,32M)
    unsigned short* vt     = (unsigned short*)(ws + 32 * MB);  // [32,40M)
    unsigned short* oat    = (unsigned short*)(ws + 40 * MB);  // [40,48M)

    convert2<<<7168, 256, 0, stream>>>(x, wqkv, xb, wqkvb);

    gemm_qkv<<<832, 256, 0, stream>>>(xb, wqkvb, fa, fb, qro, kro, vt, wproj, wprojb);

    attn_fwd<<<512, 256, 0, stream>>>(qro, kro, vt, oat);

    gemm_nt<<<256, 256, 0, stream>>>(oat, wprojb, (float*)d_out, bproj,
                                     4096, 1024, 1024);
}

// Round 22
// 114.842 us; speedup vs baseline: 1.0062x; 1.0062x over previous
//
#include <hip/hip_runtime.h>

// B=2, T=2048, C=1024, H=16, HD=64. Inputs f32, output f32.  BEST-KNOWN CONFIG (r20):
// convert2 (x,Wqkv), QKV GEMM (BK=64, XOR-swizzled LDS, XCD-local regions,
// fused RoPE/split epilogue, V^T slot-ordered, tail blocks convert W_proj),
// flash attention (KVBLK=128, K+V LDS dbuf, swizzled, lb(256,2)),
// proj GEMM (BK=64, XCD-local) -> f32.
// ws plan (48 MiB): [0,8M) xb | [8,14M) wqkvb | [14,16M) wprojb | [16,24M) qro
//                   | [24,32M) kro | [32,40M) vt | [40,48M) oat

typedef short  bf16x8 __attribute__((ext_vector_type(8)));
typedef float  f32x4  __attribute__((ext_vector_type(4)));
typedef unsigned short u16x4 __attribute__((ext_vector_type(4)));

#define B_  2
#define T_  2048
#define H_  16
#define HD_ 64
#define NINF (-__builtin_inff())

static __device__ __forceinline__ unsigned short f2bf(float f) {
    union { float f; unsigned u; } v; v.f = f;
    unsigned r = v.u + 0x7fffu + ((v.u >> 16) & 1u);   // RNE
    return (unsigned short)(r >> 16);
}

#define GLOAD_LDS16(gp, lp)                                                              \
    __builtin_amdgcn_global_load_lds((const __attribute__((address_space(1))) void*)(gp), \
                                     (__attribute__((address_space(3))) void*)(lp), 16, 0, 0)

// ---------------- f32 -> bf16 convert of x, W_qkv (single launch) ----------------
__global__ void convert2(const float* __restrict__ x, const float* __restrict__ wqkv,
                         unsigned short* __restrict__ xb, unsigned short* __restrict__ wqkvb) {
    int i = blockIdx.x * blockDim.x + threadIdx.x;     // float4 index, total 1835008
    const float* src; unsigned short* dst; int off;
    if (i < 1048576) { src = x;    dst = xb;    off = i; }
    else             { src = wqkv; dst = wqkvb; off = i - 1048576; }
    float4 f = ((const float4*)src)[off];
    u16x4 o; o[0] = f2bf(f.x); o[1] = f2bf(f.y); o[2] = f2bf(f.z); o[3] = f2bf(f.w);
    ((u16x4*)dst)[off] = o;
}

// ---------------- QKV GEMM (r17 verified) + W_proj-convert tail blocks ------
__global__ __launch_bounds__(256) void gemm_qkv(const unsigned short* __restrict__ A,
                                                const unsigned short* __restrict__ Bm,
                                                const float* __restrict__ fa,
                                                const float* __restrict__ fb,
                                                unsigned short* __restrict__ Qo,
                                                unsigned short* __restrict__ Ko,
                                                unsigned short* __restrict__ Vt,
                                                const float* __restrict__ wproj,
                                                unsigned short* __restrict__ wprojb) {
    __shared__ __align__(16) unsigned short As[128 * 64];   // 16 KB
    __shared__ __align__(16) unsigned short Bs[128 * 64];
    const int bid = blockIdx.x;
    if (bid >= 768) {                        // tail: convert W_proj (1048576 f32)
        int base = (bid - 768) * 256 + threadIdx.x;   // 16384 threads x 16 float4
#pragma unroll
        for (int k = 0; k < 16; k++) {
            int u = base + k * 16384;
            float4 f = ((const float4*)wproj)[u];
            u16x4 o; o[0] = f2bf(f.x); o[1] = f2bf(f.y); o[2] = f2bf(f.z); o[3] = f2bf(f.w);
            ((u16x4*)wprojb)[u] = o;
        }
        return;
    }

    const int K = 1024;
    const int tid  = threadIdx.x;
    const int w    = tid >> 6;
    const int lane = tid & 63;
    const int r    = lane & 15, g = lane >> 4;

    // XCD-local region mapping (bijective): 768 = 8 XCD x (8m x 12n)
    const int xcd  = bid & 7;
    const int i_   = bid >> 3;                 // 0..95
    const int m0   = ((xcd >> 1) * 8 + i_ / 12) * 128;
    const int n0   = ((xcd & 1) * 12 + i_ % 12) * 128;
    const int wm   = (w >> 1) * 64, wn = (w & 1) * 64;

    f32x4 acc[4][4];
#pragma unroll
    for (int i = 0; i < 4; i++)
#pragma unroll
        for (int j = 0; j < 4; j++) acc[i][j] = (f32x4){0.f, 0.f, 0.f, 0.f};

    const int rowS = tid >> 3;
    const int csS  = (tid & 7) ^ (rowS & 7);
    const int t8e  = tid * 8;
    const unsigned short* ga = A  + (size_t)(m0 + rowS) * K + csS * 8;
    const unsigned short* gb = Bm + (size_t)(n0 + rowS) * K + csS * 8;

    int roff[4][2];
#pragma unroll
    for (int mi = 0; mi < 4; mi++)
#pragma unroll
        for (int kk = 0; kk < 2; kk++)
            roff[mi][kk] = (mi * 16 + r) * 64 + (((4 * kk + g) ^ (r & 7)) * 8);

    for (int k0 = 0; k0 < K; k0 += 64) {
        __syncthreads();
        GLOAD_LDS16(ga + k0,            &As[t8e]);
        GLOAD_LDS16(ga + 32 * K + k0,   &As[2048 + t8e]);
        GLOAD_LDS16(ga + 64 * K + k0,   &As[4096 + t8e]);
        GLOAD_LDS16(ga + 96 * K + k0,   &As[6144 + t8e]);
        GLOAD_LDS16(gb + k0,            &Bs[t8e]);
        GLOAD_LDS16(gb + 32 * K + k0,   &Bs[2048 + t8e]);
        GLOAD_LDS16(gb + 64 * K + k0,   &Bs[4096 + t8e]);
        GLOAD_LDS16(gb + 96 * K + k0,   &Bs[6144 + t8e]);
        __syncthreads();

#pragma unroll
        for (int kk = 0; kk < 2; kk++) {
            bf16x8 a[4], b[4];
#pragma unroll
            for (int mi = 0; mi < 4; mi++) a[mi] = *(const bf16x8*)&As[wm * 64 + roff[mi][kk]];
#pragma unroll
            for (int ni = 0; ni < 4; ni++) b[ni] = *(const bf16x8*)&Bs[wn * 64 + roff[ni][kk]];
#pragma unroll
            for (int mi = 0; mi < 4; mi++)
#pragma unroll
                for (int ni = 0; ni < 4; ni++)
                    acc[mi][ni] = __builtin_amdgcn_mfma_f32_16x16x32_bf16(a[mi], b[ni], acc[mi][ni], 0, 0, 0);
        }
    }

    // -------- fused epilogue --------
    const float* fcos = (fa[0] > 0.5f) ? fa : fb;   // cos row at t=0 is all 1.0
    const float* fsin = (fa[0] > 0.5f) ? fb : fa;
    const int region = n0 >> 10;                    // 0=Q, 1=K, 2=V (block-uniform)

    if (region < 2) {
        unsigned short* dst = region ? Ko : Qo;
        const float sgn = (r & 1) ? 1.f : -1.f;     // out = v*c + sgn*vp*s
#pragma unroll
        for (int mi = 0; mi < 4; mi++) {
            int row0 = m0 + wm + mi * 16 + 4 * g;
            int b    = row0 >> 11;
            int t0   = row0 & 2047;
#pragma unroll
            for (int ni = 0; ni < 4; ni++) {
                int nn = (n0 & 1023) + wn + ni * 16 + r;
                int h  = nn >> 6, dd = nn & 63;
                int i  = dd >> 1;
                size_t obase = ((size_t)((b * 16 + h) * 2048 + t0)) * 64 + dd;
#pragma unroll
                for (int j = 0; j < 4; j++) {
                    float c = fcos[(t0 + j) * 32 + i];
                    float s = fsin[(t0 + j) * 32 + i];
                    float v  = acc[mi][ni][j];
                    float vp = __shfl_xor(v, 1);
                    float out = __builtin_fmaf(sgn * vp, s, v * c);
                    dst[obase + (size_t)j * 64] = f2bf(out);
                }
            }
        }
    } else {
#pragma unroll
        for (int mi = 0; mi < 4; mi++) {
            int row0 = m0 + wm + mi * 16 + 4 * g;
            int b    = row0 >> 11;
            int t0   = row0 & 2047;
            int tp   = (t0 & ~31) + 8 * ((t0 & 15) >> 2) + 4 * ((t0 & 31) >> 4);
#pragma unroll
            for (int ni = 0; ni < 4; ni++) {
                int nn = (n0 & 1023) + wn + ni * 16 + r;
                int h  = nn >> 6, dd = nn & 63;
                u16x4 ov;
#pragma unroll
                for (int j = 0; j < 4; j++) ov[j] = f2bf(acc[mi][ni][j]);
                *(u16x4*)(Vt + ((size_t)((b * 16 + h) * 64 + dd)) * 2048 + tp) = ov;
            }
        }
    }
}

// ---------------- proj GEMM (BK=64, XCD-local): C = A*B^T + bias -> f32 ----------------
__global__ __launch_bounds__(256) void gemm_nt(const unsigned short* __restrict__ A,
                                               const unsigned short* __restrict__ Bm,
                                               float* __restrict__ Cm,
                                               const float* __restrict__ bias,
                                               int M, int N, int K) {
    __shared__ __align__(16) unsigned short As[128 * 64];
    __shared__ __align__(16) unsigned short Bs[128 * 64];
    const int tid  = threadIdx.x;
    const int w    = tid >> 6;
    const int lane = tid & 63;
    const int r    = lane & 15, g = lane >> 4;

    const int bid  = blockIdx.x;
    const int xcd  = bid & 7;
    const int i_   = bid >> 3;                 // 0..31
    const int m0   = ((xcd >> 1) * 8 + (i_ >> 2)) * 128;
    const int n0   = ((xcd & 1) * 4 + (i_ & 3)) * 128;
    const int wm   = (w >> 1) * 64, wn = (w & 1) * 64;

    f32x4 acc[4][4];
#pragma unroll
    for (int i = 0; i < 4; i++)
#pragma unroll
        for (int j = 0; j < 4; j++) acc[i][j] = (f32x4){0.f, 0.f, 0.f, 0.f};

    const int rowS = tid >> 3;
    const int csS  = (tid & 7) ^ (rowS & 7);
    const int t8e  = tid * 8;
    const unsigned short* ga = A  + (size_t)(m0 + rowS) * K + csS * 8;
    const unsigned short* gb = Bm + (size_t)(n0 + rowS) * K + csS * 8;

    int roff[4][2];
#pragma unroll
    for (int mi = 0; mi < 4; mi++)
#pragma unroll
        for (int kk = 0; kk < 2; kk++)
            roff[mi][kk] = (mi * 16 + r) * 64 + (((4 * kk + g) ^ (r & 7)) * 8);

    for (int k0 = 0; k0 < K; k0 += 64) {
        __syncthreads();
        GLOAD_LDS16(ga + k0,            &As[t8e]);
        GLOAD_LDS16(ga + 32 * K + k0,   &As[2048 + t8e]);
        GLOAD_LDS16(ga + 64 * K + k0,   &As[4096 + t8e]);
        GLOAD_LDS16(ga + 96 * K + k0,   &As[6144 + t8e]);
        GLOAD_LDS16(gb + k0,            &Bs[t8e]);
        GLOAD_LDS16(gb + 32 * K + k0,   &Bs[2048 + t8e]);
        GLOAD_LDS16(gb + 64 * K + k0,   &Bs[4096 + t8e]);
        GLOAD_LDS16(gb + 96 * K + k0,   &Bs[6144 + t8e]);
        __syncthreads();

#pragma unroll
        for (int kk = 0; kk < 2; kk++) {
            bf16x8 a[4], b[4];
#pragma unroll
            for (int mi = 0; mi < 4; mi++) a[mi] = *(const bf16x8*)&As[wm * 64 + roff[mi][kk]];
#pragma unroll
            for (int ni = 0; ni < 4; ni++) b[ni] = *(const bf16x8*)&Bs[wn * 64 + roff[ni][kk]];
#pragma unroll
            for (int mi = 0; mi < 4; mi++)
#pragma unroll
                for (int ni = 0; ni < 4; ni++)
                    acc[mi][ni] = __builtin_amdgcn_mfma_f32_16x16x32_bf16(a[mi], b[ni], acc[mi][ni], 0, 0, 0);
        }
    }

#pragma unroll
    for (int mi = 0; mi < 4; mi++) {
        int row = m0 + wm + mi * 16 + 4 * g;
#pragma unroll
        for (int ni = 0; ni < 4; ni++) {
            int col = n0 + wn + ni * 16 + r;
            float bv = bias[col];
#pragma unroll
            for (int j = 0; j < 4; j++)
                Cm[(size_t)(row + j) * N + col] = acc[mi][ni][j] + bv;
        }
    }
}

// ---------------- flash attention, KVBLK=128 (r17 structure) ----------------
template <bool DIAG>
static __device__ __forceinline__ void softmax128(const f32x4 s[8], int key0, int qrow,
                                                  float& m, float& l,
                                                  f32x4 o[4], bf16x8 pf[4], int g) {
    const float SCL = 0.125f * 1.4426950408889634f;   // HD^-0.5 * log2(e)
    float sv[32];
#pragma unroll
    for (int ks = 0; ks < 8; ks++)
#pragma unroll
        for (int j = 0; j < 4; j++) {
            float x = s[ks][j];
            if (DIAG && (key0 + ks * 16 + 4 * g + j > qrow)) x = NINF;
            sv[ks * 4 + j] = x;
        }
    float t16[16];
#pragma unroll
    for (int i = 0; i < 16; i++) t16[i] = fmaxf(sv[i], sv[i + 16]);
#pragma unroll
    for (int i = 0; i < 8; i++) t16[i] = fmaxf(t16[i], t16[i + 8]);
#pragma unroll
    for (int i = 0; i < 4; i++) t16[i] = fmaxf(t16[i], t16[i + 4]);
    float tm = fmaxf(fmaxf(t16[0], t16[1]), fmaxf(t16[2], t16[3]));
    tm = fmaxf(tm, __shfl_xor(tm, 16));
    tm = fmaxf(tm, __shfl_xor(tm, 32));

    float msc;
    if (__all(tm <= m)) {                 // exact skip: alpha == 1 for every row
        msc = m * SCL;
    } else {
        float mnew  = fmaxf(m, tm);
        float alpha = __builtin_amdgcn_exp2f((m - mnew) * SCL);
        l *= alpha;
#pragma unroll
        for (int ch = 0; ch < 4; ch++) o[ch] *= alpha;
        m = mnew;
        msc = mnew * SCL;
    }
    float p[32];
#pragma unroll
    for (int i = 0; i < 32; i++) p[i] = __builtin_amdgcn_exp2f(__builtin_fmaf(sv[i], SCL, -msc));
    float ps = 0.f;
#pragma unroll
    for (int i = 0; i < 32; i += 4) ps += ((p[i] + p[i + 1]) + (p[i + 2] + p[i + 3]));
    l += ps;
#pragma unroll
    for (int kb = 0; kb < 4; kb++) {
        union { unsigned w[4]; bf16x8 v; } u;
        asm("v_cvt_pk_bf16_f32 %0, %1, %2" : "=v"(u.w[0]) : "v"(p[8 * kb + 0]), "v"(p[8 * kb + 1]));
        asm("v_cvt_pk_bf16_f32 %0, %1, %2" : "=v"(u.w[1]) : "v"(p[8 * kb + 2]), "v"(p[8 * kb + 3]));
        asm("v_cvt_pk_bf16_f32 %0, %1, %2" : "=v"(u.w[2]) : "v"(p[8 * kb + 4]), "v"(p[8 * kb + 5]));
        asm("v_cvt_pk_bf16_f32 %0, %1, %2" : "=v"(u.w[3]) : "v"(p[8 * kb + 6]), "v"(p[8 * kb + 7]));
        pf[kb] = u.v;
    }
}

__global__ __launch_bounds__(256, 2) void attn_fwd(const unsigned short* __restrict__ Q,
                                                   const unsigned short* __restrict__ Kk,
                                                   const unsigned short* __restrict__ Vt,
                                                   unsigned short* __restrict__ O) {
    __shared__ __align__(16) unsigned short Ks[2][8192];   // dbuf: 128 keys x 64 d (swizzled)
    __shared__ __align__(16) unsigned short Vs[2][8192];   // dbuf: 64 d x 128 keys (swizzled, slot-ordered)

    const int w    = threadIdx.x >> 6;
    const int lane = threadIdx.x & 63;
    const int l15  = lane & 15, g = lane >> 4;

    const int bid = blockIdx.x;
    const int x   = bid & 7;
    const int y   = (bid >> 3) & 31;
    const int q   = bid >> 8;                 // 0..3
    const int bh  = x | ((y & 3) << 3);       // 32 bh, 4 per XCD
    const int z   = y >> 2;                   // 0..7
    const int r   = (q == 0) ? z : (q == 1) ? 15 - z : (q == 2) ? 16 + z : 31 - z;
    const int b   = bh >> 4, h = bh & 15;

    const unsigned short* Qb = Q  + (size_t)bh * T_ * HD_;
    const unsigned short* Kb = Kk + (size_t)bh * T_ * HD_;
    const unsigned short* Vb = Vt + (size_t)bh * HD_ * T_;

    const int qrow = r * 64 + 16 * w + l15;
    bf16x8 qf0 = *(const bf16x8*)(Qb + (size_t)qrow * 64 + 8 * g);
    bf16x8 qf1 = *(const bf16x8*)(Qb + (size_t)qrow * 64 + 32 + 8 * g);

    f32x4 o[4];
#pragma unroll
    for (int ch = 0; ch < 4; ch++) o[ch] = (f32x4){0, 0, 0, 0};
    float m2 = NINF, lsum = 0.f;

    int koff[8][2];                            // K: row=16ks+l15, 128B rows, chunks {g, 4+g}
#pragma unroll
    for (int i = 0; i < 8; i++) {
        int row = 16 * i + l15;
        koff[i][0] = row * 128 + ((g ^ (row & 7)) << 4);
        koff[i][1] = row * 128 + (((4 + g) ^ (row & 7)) << 4);
    }
    int voff[4][4];                            // V: row=16ch+l15, 256B rows, chunk kb*4+g
#pragma unroll
    for (int ch = 0; ch < 4; ch++) {
        int row = 16 * ch + l15;
#pragma unroll
        for (int kb = 0; kb < 4; kb++)
            voff[ch][kb] = row * 256 + (((kb * 4 + g) ^ (row & 7)) << 4);
    }

    const int t   = threadIdx.x;
    const int rK0 = t >> 3;
    const int csK = (t & 7) ^ (rK0 & 7);
    const int rV0 = t >> 4;
    const int csV = (t & 15) ^ (rV0 & 7);
    const int t8e = t * 8;
    const unsigned short* sK = Kb + (size_t)rK0 * 64 + csK * 8;     // + key0*64 + 2048*k
    const unsigned short* sV = Vb + (size_t)rV0 * 2048 + csV * 8;   // + key0 + 32768*k

#define STAGE_TILE(bb, key0_)                                                     \
    do {                                                                          \
        GLOAD_LDS16(sK + (size_t)(key0_) * 64,         &Ks[bb][t8e]);             \
        GLOAD_LDS16(sK + (size_t)(key0_) * 64 + 2048,  &Ks[bb][2048 + t8e]);      \
        GLOAD_LDS16(sK + (size_t)(key0_) * 64 + 4096,  &Ks[bb][4096 + t8e]);      \
        GLOAD_LDS16(sK + (size_t)(key0_) * 64 + 6144,  &Ks[bb][6144 + t8e]);      \
        GLOAD_LDS16(sV + (key0_),                      &Vs[bb][t8e]);             \
        GLOAD_LDS16(sV + (key0_) + 32768,              &Vs[bb][2048 + t8e]);      \
        GLOAD_LDS16(sV + (key0_) + 65536,              &Vs[bb][4096 + t8e]);      \
        GLOAD_LDS16(sV + (key0_) + 98304,              &Vs[bb][6144 + t8e]);      \
    } while (0)

    const int ktEnd = r >> 1;          // diagonal 128-key tile
    STAGE_TILE(0, 0);
    __syncthreads();                   // drains vmcnt -> tile 0 ready

    for (int kt = 0; kt <= ktEnd; ++kt) {
        const int key0 = kt * 128;
        const int cur  = kt & 1;
        if (kt < ktEnd) STAGE_TILE(cur ^ 1, key0 + 128);   // prefetch next tile

        const char* KsB = (const char*)&Ks[cur][0];
        const char* VsB = (const char*)&Vs[cur][0];

        f32x4 z4 = (f32x4){0, 0, 0, 0};
        f32x4 s[8];
#pragma unroll
        for (int ks = 0; ks < 8; ks++) {
            bf16x8 kf0 = *(const bf16x8*)(KsB + koff[ks][0]);
            bf16x8 kf1 = *(const bf16x8*)(KsB + koff[ks][1]);
            s[ks] = __builtin_amdgcn_mfma_f32_16x16x32_bf16(kf0, qf0, z4, 0, 0, 0);
            s[ks] = __builtin_amdgcn_mfma_f32_16x16x32_bf16(kf1, qf1, s[ks], 0, 0, 0);
        }

        bf16x8 pf[4];
        if (kt == ktEnd) softmax128<true >(s, key0, qrow, m2, lsum, o, pf, g);
        else             softmax128<false>(s, key0, qrow, m2, lsum, o, pf, g);

#pragma unroll
        for (int ch = 0; ch < 4; ch++) {
            bf16x8 v0 = *(const bf16x8*)(VsB + voff[ch][0]);
            bf16x8 v1 = *(const bf16x8*)(VsB + voff[ch][1]);
            bf16x8 v2 = *(const bf16x8*)(VsB + voff[ch][2]);
            bf16x8 v3 = *(const bf16x8*)(VsB + voff[ch][3]);
            o[ch] = __builtin_amdgcn_mfma_f32_16x16x32_bf16(v0, pf[0], o[ch], 0, 0, 0);
            o[ch] = __builtin_amdgcn_mfma_f32_16x16x32_bf16(v1, pf[1], o[ch], 0, 0, 0);
            o[ch] = __builtin_amdgcn_mfma_f32_16x16x32_bf16(v2, pf[2], o[ch], 0, 0, 0);
            o[ch] = __builtin_amdgcn_mfma_f32_16x16x32_bf16(v3, pf[3], o[ch], 0, 0, 0);
        }

        __syncthreads();    // drains vmcnt (next tile staged) + read/write fence
    }
#undef STAGE_TILE

    lsum += __shfl_xor(lsum, 16);
    lsum += __shfl_xor(lsum, 32);
    float inv = 1.f / lsum;

    size_t obase = (((size_t)b * T_ + qrow) * H_ + h) * HD_;
#pragma unroll
    for (int ch = 0; ch < 4; ch++) {
        int d0 = 16 * ch + 4 * g;
        u16x4 ov;
#pragma unroll
        for (int jj = 0; jj < 4; jj++) ov[jj] = f2bf(o[ch][jj] * inv);
        *(u16x4*)(O + obase + d0) = ov;
    }
}

extern "C" void kernel_launch(void* const* d_in, const int* in_sizes, int n_in,
                              void* d_out, int out_size, void* d_ws, size_t ws_size,
                              hipStream_t stream) {
    (void)out_size;
    const float *x = nullptr, *wqkv = nullptr, *wproj = nullptr, *bproj = nullptr;
    const float *fa = nullptr, *fb = nullptr;
    for (int i = 0; i < n_in; i++) {
        switch (in_sizes[i]) {
            case 4194304: x     = (const float*)d_in[i]; break;
            case 3145728: wqkv  = (const float*)d_in[i]; break;
            case 1048576: wproj = (const float*)d_in[i]; break;
            case 1024:    bproj = (const float*)d_in[i]; break;
            case 65536:   if (!fa) fa = (const float*)d_in[i]; else fb = (const float*)d_in[i]; break;
            default: break;
        }
    }
    if (!x || !wqkv || !wproj || !bproj || !fa || !fb) return;
    if (ws_size < (size_t)48 * 1024 * 1024) return;

    char* ws = (char*)d_ws;
    const size_t MB = 1024 * 1024;
    unsigned short* xb     = (unsigned short*)(ws);            // [0,8M)
    unsigned short* wqkvb  = (unsigned short*)(ws + 8  * MB);  // [8,14M)
    unsigned short* wprojb = (unsigned short*)(ws + 14 * MB);  // [14,16M)
    unsigned short* qro    = (unsigned short*)(ws + 16 * MB);  // [16,24M)
    unsigned short* kro    = (unsigned short*)(ws + 24 * MB);  // [24,32M)
    unsigned short* vt     = (unsigned short*)(ws + 32 * MB);  // [32,40M)
    unsigned short* oat    = (unsigned short*)(ws + 40 * MB);  // [40,48M)

    convert2<<<7168, 256, 0, stream>>>(x, wqkv, xb, wqkvb);

    gemm_qkv<<<832, 256, 0, stream>>>(xb, wqkvb, fa, fb, qro, kro, vt, wproj, wprojb);

    attn_fwd<<<1024, 256, 0, stream>>>(qro, kro, vt, oat);

    gemm_nt<<<256, 256, 0, stream>>>(oat, wprojb, (float*)d_out, bproj,
                                     4096, 1024, 1024);
}